// Round 2
// baseline (11725.443 us; speedup 1.0000x reference)
//
#include <hip/hip_runtime.h>
#include <math.h>

// ---- problem constants ----
#define BB 32
#define TT 720
#define CC 862
#define MM 4
#define LTOK 866          // C + M tokens
#define DD 512
#define HH 8
#define EE 64
#define FFD 2048
#define NTOK (BB * LTOK)  // 27712, M-dim of all big GEMMs  (= 433 * 64)
#define NBH (BB * HH)     // 256

__device__ __forceinline__ float wave_sum(float v) {
    #pragma unroll
    for (int off = 32; off; off >>= 1) v += __shfl_xor(v, off, 64);
    return v;
}

// ============ RevIN stats: mean/stdev per (b,c) over T ============
__global__ __launch_bounds__(256) void revin_stats(const float* __restrict__ x_enc,
                                                   float* __restrict__ mean,
                                                   float* __restrict__ stdev) {
    int b = blockIdx.y;
    int c = blockIdx.x * 64 + (threadIdx.x & 63);
    int g = threadIdx.x >> 6;
    float s = 0.f, s2 = 0.f;
    if (c < CC) {
        for (int t = g; t < TT; t += 4) {
            float v = x_enc[((size_t)b * TT + t) * CC + c];
            s += v; s2 += v * v;
        }
    }
    __shared__ float ls[4][64], ls2[4][64];
    ls[g][threadIdx.x & 63] = s; ls2[g][threadIdx.x & 63] = s2;
    __syncthreads();
    if (g == 0 && c < CC) {
        int cx = threadIdx.x & 63;
        s = ls[0][cx] + ls[1][cx] + ls[2][cx] + ls[3][cx];
        s2 = ls2[0][cx] + ls2[1][cx] + ls2[2][cx] + ls2[3][cx];
        float mu = s / (float)TT;
        float var = s2 / (float)TT - mu * mu;
        mean[b * CC + c] = mu;
        stdev[b * CC + c] = sqrtf(var + 1e-5f);
    }
}

// ============ build tok[B,866,720]: normalized channels + marks (transpose) ============
__global__ __launch_bounds__(256) void build_tok(const float* __restrict__ x_enc,
                                                 const float* __restrict__ x_mark,
                                                 const float* __restrict__ mean,
                                                 const float* __restrict__ stdev,
                                                 const float* __restrict__ rw,
                                                 const float* __restrict__ rb,
                                                 float* __restrict__ tok) {
    int b = blockIdx.z;
    int r0 = blockIdx.x * 32, t0 = blockIdx.y * 32;
    __shared__ float tile[32][33];
    int tx = threadIdx.x & 31, ty = threadIdx.x >> 5;   // ty 0..7
    #pragma unroll
    for (int kk = 0; kk < 4; kk++) {
        int t = t0 + ty + kk * 8, r = r0 + tx;
        float v = 0.f;
        if (t < TT && r < LTOK) {
            if (r < CC) {
                float xv = x_enc[((size_t)b * TT + t) * CC + r];
                v = (xv - mean[b * CC + r]) / stdev[b * CC + r] * rw[r] + rb[r];
            } else {
                v = x_mark[((size_t)b * TT + t) * MM + (r - CC)];
            }
        }
        tile[ty + kk * 8][tx] = v;
    }
    __syncthreads();
    #pragma unroll
    for (int kk = 0; kk < 4; kk++) {
        int r = r0 + ty + kk * 8, t = t0 + tx;
        if (r < LTOK && t < TT)
            tok[((size_t)b * LTOK + r) * TT + t] = tile[tx][ty + kk * 8];
    }
}

// ============ generic fp32 GEMM: C = act(A[M,K] @ B[K,N] + bias[N]) ============
// tile 64x64, 256 threads, 4x4 micro-tile. Requires M%64==0, K%16==0, N%4==0.
template <int ACT>   // 0 none, 1 gelu(exact), 2 sigmoid
__global__ __launch_bounds__(256) void gemm_kernel(const float* __restrict__ A,
                                                   const float* __restrict__ Bm,
                                                   const float* __restrict__ bias,
                                                   float* __restrict__ C,
                                                   int Mdim, int Ndim, int Kdim) {
    __shared__ float As[16][64];   // [k][m]
    __shared__ float Bs[16][64];   // [k][n]
    int tid = threadIdx.x;
    int tx = tid & 15, ty = tid >> 4;
    int m0 = blockIdx.y * 64, n0 = blockIdx.x * 64;

    float acc[4][4] = {};
    int a_m = tid & 63;
    int a_ks = (tid >> 6) * 4;
    const float* Aptr = A + (size_t)(m0 + a_m) * Kdim + a_ks;
    int b_k = tid >> 4;            // 0..15
    int b_n = (tid & 15) * 4;
    const float* Bptr = Bm + (size_t)b_k * Ndim + n0 + b_n;
    bool bvalid = (n0 + b_n + 3) < Ndim;

    for (int k0 = 0; k0 < Kdim; k0 += 16) {
        float4 av = *(const float4*)(Aptr + k0);
        float4 bv = make_float4(0.f, 0.f, 0.f, 0.f);
        if (bvalid) bv = *(const float4*)(Bptr + (size_t)k0 * Ndim);
        __syncthreads();
        As[a_ks + 0][a_m] = av.x;
        As[a_ks + 1][a_m] = av.y;
        As[a_ks + 2][a_m] = av.z;
        As[a_ks + 3][a_m] = av.w;
        *(float4*)&Bs[b_k][b_n] = bv;
        __syncthreads();
        #pragma unroll
        for (int kk = 0; kk < 16; kk++) {
            float4 a = *(const float4*)&As[kk][ty * 4];
            float4 b = *(const float4*)&Bs[kk][tx * 4];
            acc[0][0] += a.x * b.x; acc[0][1] += a.x * b.y; acc[0][2] += a.x * b.z; acc[0][3] += a.x * b.w;
            acc[1][0] += a.y * b.x; acc[1][1] += a.y * b.y; acc[1][2] += a.y * b.z; acc[1][3] += a.y * b.w;
            acc[2][0] += a.z * b.x; acc[2][1] += a.z * b.y; acc[2][2] += a.z * b.z; acc[2][3] += a.z * b.w;
            acc[3][0] += a.w * b.x; acc[3][1] += a.w * b.y; acc[3][2] += a.w * b.z; acc[3][3] += a.w * b.w;
        }
    }
    bool col_ok = (n0 + tx * 4 + 3) < Ndim;
    float4 bb = make_float4(0.f, 0.f, 0.f, 0.f);
    if (col_ok) bb = *(const float4*)&bias[n0 + tx * 4];
    #pragma unroll
    for (int i = 0; i < 4; i++) {
        int row = m0 + ty * 4 + i;
        float r[4] = {acc[i][0] + bb.x, acc[i][1] + bb.y, acc[i][2] + bb.z, acc[i][3] + bb.w};
        #pragma unroll
        for (int j = 0; j < 4; j++) {
            if (ACT == 1) r[j] = 0.5f * r[j] * (1.0f + erff(r[j] * 0.70710678118654752f));
            if (ACT == 2) r[j] = 1.0f / (1.0f + expf(-r[j]));
        }
        if (col_ok) {
            float4 st = make_float4(r[0], r[1], r[2], r[3]);
            *(float4*)&C[(size_t)row * Ndim + n0 + tx * 4] = st;
        }
    }
}

// ============ LayerNorm over D=512: x = LN(x [+ res]) * w + b, in place ============
__global__ __launch_bounds__(256) void ln_kernel(float* __restrict__ x,
                                                 const float* __restrict__ res,
                                                 const float* __restrict__ w,
                                                 const float* __restrict__ bp) {
    size_t base = (size_t)blockIdx.x * DD;
    int tid = threadIdx.x;
    float v0 = x[base + tid];
    float v1 = x[base + tid + 256];
    if (res != nullptr) { v0 += res[base + tid]; v1 += res[base + tid + 256]; }
    float s = wave_sum(v0 + v1);
    float s2 = wave_sum(v0 * v0 + v1 * v1);
    __shared__ float a1[4], a2[4];
    if ((tid & 63) == 0) { a1[tid >> 6] = s; a2[tid >> 6] = s2; }
    __syncthreads();
    s = a1[0] + a1[1] + a1[2] + a1[3];
    s2 = a2[0] + a2[1] + a2[2] + a2[3];
    float mu = s * (1.0f / DD);
    float var = s2 * (1.0f / DD) - mu * mu;
    float rs = rsqrtf(var + 1e-5f);
    x[base + tid] = (v0 - mu) * rs * w[tid] + bp[tid];
    x[base + tid + 256] = (v1 - mu) * rs * w[tid + 256] + bp[tid + 256];
}

// ============ attention: per (b,h) column sums (optionally weighted per-l) ============
template <bool WEIGHTED>
__global__ __launch_bounds__(256) void attn_sums(const float* __restrict__ Q,
                                                 const float* __restrict__ Kp,
                                                 const float* __restrict__ wq,
                                                 const float* __restrict__ wk,
                                                 float* __restrict__ qsum,
                                                 float* __restrict__ ksum) {
    int bh = blockIdx.x;
    int b = bh >> 3, h = bh & 7;
    int e = threadIdx.x & 63, g = threadIdx.x >> 6;
    const size_t base = ((size_t)b * LTOK) * DD + h * 64 + e;
    float sq = 0.f, sk = 0.f;
    for (int l = g; l < LTOK; l += 4) {
        float qv = Q[base + (size_t)l * DD];
        float kv = Kp[base + (size_t)l * DD];
        if (WEIGHTED) { qv *= wq[bh * LTOK + l]; kv *= wk[bh * LTOK + l]; }
        sq += qv; sk += kv;
    }
    __shared__ float s1[4][64], s2[4][64];
    s1[g][e] = sq; s2[g][e] = sk;
    __syncthreads();
    if (g == 0) {
        sq = s1[0][e] + s1[1][e] + s1[2][e] + s1[3][e];
        sk = s2[0][e] + s2[1][e] + s2[2][e] + s2[3][e];
        qsum[bh * 64 + e] = sq;
        ksum[bh * 64 + e] = sk;
    }
}

// ============ attention: per-l dot with summed vector ============
// MODE 0: outq[l] = 1/dot(q+eps, Sq+eps); outk[l] = 1/dot(k+eps, Sk+eps)
// MODE 1: outq[l] = sigmoid(dot(q+eps, Sq+eps) * Lq/Ls = 1); outk[l] = dot(k+eps, Sk+eps)
template <int MODE>
__global__ __launch_bounds__(256) void attn_dots(const float* __restrict__ Q,
                                                 const float* __restrict__ Kp,
                                                 const float* __restrict__ Sq,
                                                 const float* __restrict__ Sk,
                                                 float* __restrict__ outq,
                                                 float* __restrict__ outk) {
    int bh = blockIdx.x;
    int b = bh >> 3, h = bh & 7;
    int lane = threadIdx.x & 63, w = threadIdx.x >> 6;
    float sq = Sq[bh * 64 + lane] + 1e-6f;
    float sk = Sk[bh * 64 + lane] + 1e-6f;
    const size_t base = ((size_t)b * LTOK) * DD + h * 64 + lane;
    int l0 = blockIdx.y * 64 + w * 16;
    for (int i = 0; i < 16; i++) {
        int l = l0 + i;
        if (l >= LTOK) break;
        float dq = (Q[base + (size_t)l * DD] + 1e-6f) * sq;
        float dk = (Kp[base + (size_t)l * DD] + 1e-6f) * sk;
        dq = wave_sum(dq);
        dk = wave_sum(dk);
        if (lane == 0) {
            if (MODE == 0) { outq[bh * LTOK + l] = 1.0f / dq; outk[bh * LTOK + l] = 1.0f / dk; }
            else { outq[bh * LTOK + l] = 1.0f / (1.0f + expf(-dq)); outk[bh * LTOK + l] = dk; }
        }
    }
}

// ============ attention: softmax over s (in place), scaled by Ls ============
__global__ __launch_bounds__(256) void attn_softmax(float* __restrict__ buf) {
    float* p = buf + (size_t)blockIdx.x * LTOK;
    int tid = threadIdx.x;
    __shared__ float red[4];
    float mx = -1e30f;
    for (int l = tid; l < LTOK; l += 256) mx = fmaxf(mx, p[l]);
    #pragma unroll
    for (int off = 32; off; off >>= 1) mx = fmaxf(mx, __shfl_xor(mx, off, 64));
    if ((tid & 63) == 0) red[tid >> 6] = mx;
    __syncthreads();
    mx = fmaxf(fmaxf(red[0], red[1]), fmaxf(red[2], red[3]));
    __syncthreads();
    float s = 0.f;
    for (int l = tid; l < LTOK; l += 256) s += expf(p[l] - mx);
    s = wave_sum(s);
    if ((tid & 63) == 0) red[tid >> 6] = s;
    __syncthreads();
    s = red[0] + red[1] + red[2] + red[3];
    float scale = (float)LTOK / s;
    for (int l = tid; l < LTOK; l += 256) p[l] = expf(p[l] - mx) * scale;
}

// ============ attention: kv[e,d] = sum_s k[s,e] * v[s,d] * ncref[s] ============
__global__ __launch_bounds__(256) void attn_kv(const float* __restrict__ Kp,
                                               const float* __restrict__ V,
                                               const float* __restrict__ ncref,
                                               float* __restrict__ kv) {
    int bh = blockIdx.x;
    int b = bh >> 3, h = bh & 7;
    int d = threadIdx.x & 63, eg = threadIdx.x >> 6;
    __shared__ float ks[8][64], vs[8][64];
    float acc[16] = {};
    const size_t base = ((size_t)b * LTOK) * DD + h * 64;
    for (int s0 = 0; s0 < LTOK; s0 += 8) {
        __syncthreads();
        #pragma unroll
        for (int j = 0; j < 2; j++) {
            int idx = threadIdx.x + j * 256;
            int s = s0 + (idx >> 6), e = idx & 63;
            float kvl = 0.f, vvl = 0.f;
            if (s < LTOK) {
                kvl = Kp[base + (size_t)s * DD + e];
                vvl = V[base + (size_t)s * DD + e] * ncref[bh * LTOK + s];
            }
            ks[idx >> 6][e] = kvl;
            vs[idx >> 6][e] = vvl;
        }
        __syncthreads();
        #pragma unroll
        for (int si = 0; si < 8; si++) {
            float vv = vs[si][d];
            #pragma unroll
            for (int i = 0; i < 16; i++) acc[i] += ks[si][eg * 16 + i] * vv;
        }
    }
    #pragma unroll
    for (int i = 0; i < 16; i++)
        kv[(size_t)bh * 4096 + (eg * 16 + i) * 64 + d] = acc[i];
}

// ============ attention: out[l,d] = dot(q[l,:], kv[:,d]) * nr[l]*nrref[l] ============
__global__ __launch_bounds__(256) void attn_out(const float* __restrict__ Q,
                                                const float* __restrict__ kv,
                                                const float* __restrict__ nr,
                                                const float* __restrict__ nrref,
                                                float* __restrict__ out) {
    int bh = blockIdx.x;
    int b = bh >> 3, h = bh & 7;
    int d = threadIdx.x & 63, lg = threadIdx.x >> 6;
    __shared__ float kvs[64][64];
    __shared__ float qs[64][64];
    #pragma unroll
    for (int j = 0; j < 16; j++) {
        int idx = threadIdx.x + j * 256;
        kvs[idx >> 6][idx & 63] = kv[(size_t)bh * 4096 + idx];
    }
    int l0 = blockIdx.y * 64;
    const size_t base = ((size_t)b * LTOK) * DD + h * 64;
    for (int j = 0; j < 16; j++) {
        int idx = threadIdx.x + j * 256;
        int lr = idx >> 6, e = idx & 63;
        int l = l0 + lr;
        qs[lr][e] = (l < LTOK) ? Q[base + (size_t)l * DD + e] : 0.f;
    }
    __syncthreads();
    for (int i = 0; i < 16; i++) {
        int lr = lg * 16 + i;
        int l = l0 + lr;
        if (l >= LTOK) continue;
        float acc = 0.f;
        #pragma unroll
        for (int e = 0; e < 64; e++) acc += qs[lr][e] * kvs[e][d];
        float sc = nr[bh * LTOK + l] * nrref[bh * LTOK + l];
        out[base + (size_t)l * DD + d] = acc * sc;
    }
}

// ============ final: transpose, RevIN denorm ============
__global__ __launch_bounds__(256) void final_out(const float* __restrict__ p,
                                                 const float* __restrict__ mean,
                                                 const float* __restrict__ stdev,
                                                 const float* __restrict__ rw,
                                                 const float* __restrict__ rb,
                                                 float* __restrict__ out) {
    int b = blockIdx.z;
    int c0 = blockIdx.x * 32, t0 = blockIdx.y * 32;
    __shared__ float tile[32][33];
    int tx = threadIdx.x & 31, ty = threadIdx.x >> 5;
    #pragma unroll
    for (int kk = 0; kk < 4; kk++) {
        int c = c0 + ty + kk * 8, t = t0 + tx;
        float v = 0.f;
        if (c < CC && t < TT) v = p[((size_t)b * LTOK + c) * TT + t];
        tile[ty + kk * 8][tx] = v;
    }
    __syncthreads();
    #pragma unroll
    for (int kk = 0; kk < 4; kk++) {
        int t = t0 + ty + kk * 8, c = c0 + tx;
        if (c < CC && t < TT) {
            float v = tile[tx][ty + kk * 8];
            v = (v - rb[c]) / (rw[c] + 1e-10f);
            v = v * stdev[b * CC + c] + mean[b * CC + c];
            out[((size_t)b * TT + t) * CC + c] = v;
        }
    }
}

extern "C" void kernel_launch(void* const* d_in, const int* in_sizes, int n_in,
                              void* d_out, int out_size, void* d_ws, size_t ws_size,
                              hipStream_t stream) {
    (void)in_sizes; (void)n_in; (void)out_size; (void)ws_size;
    const float* x_enc   = (const float*)d_in[0];
    const float* x_mark  = (const float*)d_in[1];
    const float* revin_w = (const float*)d_in[4];
    const float* revin_b = (const float*)d_in[5];
    const float* emb_W   = (const float*)d_in[6];
    const float* emb_b   = (const float*)d_in[7];
    const float* Wq = (const float*)d_in[8];
    const float* bq = (const float*)d_in[9];
    const float* Wk = (const float*)d_in[10];
    const float* bk = (const float*)d_in[11];
    const float* Wv = (const float*)d_in[12];
    const float* bv = (const float*)d_in[13];
    const float* Wo = (const float*)d_in[14];
    const float* bo = (const float*)d_in[15];
    const float* ff1_W = (const float*)d_in[16];
    const float* ff1_b = (const float*)d_in[17];
    const float* ff2_W = (const float*)d_in[18];
    const float* ff2_b = (const float*)d_in[19];
    const float* ln1_w = (const float*)d_in[20];
    const float* ln1_b = (const float*)d_in[21];
    const float* ln2_w = (const float*)d_in[22];
    const float* ln2_b = (const float*)d_in[23];
    const float* lnf_w = (const float*)d_in[24];
    const float* lnf_b = (const float*)d_in[25];
    const float* proj_W = (const float*)d_in[26];
    const float* proj_b = (const float*)d_in[27];
    float* out = (float*)d_out;

    // ---- workspace layout (total ~235 MB; d_ws assumed >= 256 MB) ----
    float* ws = (float*)d_ws;
    size_t off = 0;
    auto alloc = [&](size_t n) { float* p = ws + off; off += (n + 3) & ~(size_t)3; return p; };
    float* mean  = alloc((size_t)BB * CC);
    float* stdev = alloc((size_t)BB * CC);
    float* qsum  = alloc((size_t)NBH * 64);
    float* ksum  = alloc((size_t)NBH * 64);
    float* qnsum = alloc((size_t)NBH * 64);
    float* knsum = alloc((size_t)NBH * 64);
    float* nr    = alloc((size_t)NBH * LTOK);
    float* nc    = alloc((size_t)NBH * LTOK);
    float* nrref = alloc((size_t)NBH * LTOK);
    float* ncref = alloc((size_t)NBH * LTOK);       // raw, then softmaxed in place
    float* kvbuf = alloc((size_t)NBH * 64 * 64);
    float* x     = alloc((size_t)NTOK * DD);
    float* q     = alloc((size_t)NTOK * DD);
    float* k     = alloc((size_t)NTOK * DD);        // also Wo/FF2 tmp
    float* v     = alloc((size_t)NTOK * DD);        // also attention output
    // aliases into dead regions:
    float* tok   = q;   // [NTOK,720] = 19.95M floats <= q+k region (28.38M) ; live only
                        // (a) pre-embedding, (b) as proj output — q,k dead both times
    float* ffbuf = q;   // FF1 chunk activations: 6912*2048 = 14.16M <= q (14.19M)

    dim3 blk(256);
    revin_stats<<<dim3((CC + 63) / 64, BB), blk, 0, stream>>>(x_enc, mean, stdev);
    build_tok<<<dim3((LTOK + 31) / 32, (TT + 31) / 32, BB), blk, 0, stream>>>(
        x_enc, x_mark, mean, stdev, revin_w, revin_b, tok);
    // embedding: [NTOK,720] @ [720,512]
    gemm_kernel<0><<<dim3(DD / 64, NTOK / 64), blk, 0, stream>>>(tok, emb_W, emb_b, x, NTOK, DD, TT);

    int ltiles = (LTOK + 63) / 64;
    for (int l = 0; l < 3; l++) {
        const float* wq_l = Wq + (size_t)l * DD * DD;
        const float* wk_l = Wk + (size_t)l * DD * DD;
        const float* wv_l = Wv + (size_t)l * DD * DD;
        const float* wo_l = Wo + (size_t)l * DD * DD;
        gemm_kernel<2><<<dim3(DD / 64, NTOK / 64), blk, 0, stream>>>(x, wq_l, bq + l * DD, q, NTOK, DD, DD);
        gemm_kernel<2><<<dim3(DD / 64, NTOK / 64), blk, 0, stream>>>(x, wk_l, bk + l * DD, k, NTOK, DD, DD);
        gemm_kernel<0><<<dim3(DD / 64, NTOK / 64), blk, 0, stream>>>(x, wv_l, bv + l * DD, v, NTOK, DD, DD);
        attn_sums<false><<<NBH, blk, 0, stream>>>(q, k, nullptr, nullptr, qsum, ksum);
        attn_dots<0><<<dim3(NBH, ltiles), blk, 0, stream>>>(q, k, ksum, qsum, nr, nc);
        attn_sums<true><<<NBH, blk, 0, stream>>>(q, k, nr, nc, qnsum, knsum);
        attn_dots<1><<<dim3(NBH, ltiles), blk, 0, stream>>>(q, k, knsum, qnsum, nrref, ncref);
        attn_softmax<<<NBH, blk, 0, stream>>>(ncref);
        attn_kv<<<NBH, blk, 0, stream>>>(k, v, ncref, kvbuf);
        attn_out<<<dim3(NBH, ltiles), blk, 0, stream>>>(q, kvbuf, nr, nrref, v);
        // Wo projection into tmp (k), then x = LN(x + tmp)
        gemm_kernel<0><<<dim3(DD / 64, NTOK / 64), blk, 0, stream>>>(v, wo_l, bo + l * DD, k, NTOK, DD, DD);
        ln_kernel<<<NTOK, blk, 0, stream>>>(x, k, ln1_w + l * DD, ln1_b + l * DD);
        // FF — chunked over M so the FF1 activation fits in the (dead) q buffer
        for (int t0 = 0; t0 < NTOK / 64; t0 += 108) {
            int nt = NTOK / 64 - t0; if (nt > 108) nt = 108;
            int rs = t0 * 64;
            gemm_kernel<1><<<dim3(FFD / 64, nt), blk, 0, stream>>>(
                x + (size_t)rs * DD, ff1_W + (size_t)l * DD * FFD, ff1_b + l * FFD,
                ffbuf, nt * 64, FFD, DD);
            gemm_kernel<0><<<dim3(DD / 64, nt), blk, 0, stream>>>(
                ffbuf, ff2_W + (size_t)l * FFD * DD, ff2_b + l * DD,
                k + (size_t)rs * DD, nt * 64, DD, FFD);
        }
        ln_kernel<<<NTOK, blk, 0, stream>>>(x, k, ln2_w + l * DD, ln2_b + l * DD);
    }
    ln_kernel<<<NTOK, blk, 0, stream>>>(x, nullptr, lnf_w, lnf_b);
    // projection: [NTOK,512] @ [512,720] -> tok region (q/k dead now)
    gemm_kernel<0><<<dim3((TT + 63) / 64, NTOK / 64), blk, 0, stream>>>(x, proj_W, proj_b, tok, NTOK, TT, DD);
    final_out<<<dim3((CC + 31) / 32, (TT + 31) / 32, BB), blk, 0, stream>>>(
        tok, mean, stdev, revin_w, revin_b, out);
}

// Round 3
// 4232.577 us; speedup vs baseline: 2.7703x; 2.7703x over previous
//
#include <hip/hip_runtime.h>
#include <math.h>

// ---- problem constants ----
#define BB 32
#define TT 720
#define CC 862
#define MM 4
#define LTOK 866          // C + M tokens
#define DD 512
#define HH 8
#define EE 64
#define FFD 2048
#define NTOK (BB * LTOK)  // 27712 = 433*64
#define NBH (BB * HH)     // 256
#define KPAD 736          // 720 padded to mult of 32 (embedding K)
#define NPADP 768         // 720 padded to mult of 128 (proj N tiles)

typedef unsigned short ushort_t;
typedef short s8v __attribute__((ext_vector_type(8)));
typedef float f4v __attribute__((ext_vector_type(4)));

__device__ __forceinline__ float wave_sum(float v) {
    #pragma unroll
    for (int off = 32; off; off >>= 1) v += __shfl_xor(v, off, 64);
    return v;
}
__device__ __forceinline__ float b2f(ushort_t u) {
    return __uint_as_float(((unsigned int)u) << 16);
}
__device__ __forceinline__ ushort_t f2b(float f) {
    unsigned int u = __float_as_uint(f);
    u = (u + 0x7FFFu + ((u >> 16) & 1u)) >> 16;
    return (ushort_t)u;
}

// ============ RevIN stats: mean/stdev per (b,c) over T ============
__global__ __launch_bounds__(256) void revin_stats(const float* __restrict__ x_enc,
                                                   float* __restrict__ mean,
                                                   float* __restrict__ stdev) {
    int b = blockIdx.y;
    int c = blockIdx.x * 64 + (threadIdx.x & 63);
    int g = threadIdx.x >> 6;
    float s = 0.f, s2 = 0.f;
    if (c < CC) {
        for (int t = g; t < TT; t += 4) {
            float v = x_enc[((size_t)b * TT + t) * CC + c];
            s += v; s2 += v * v;
        }
    }
    __shared__ float ls[4][64], ls2[4][64];
    ls[g][threadIdx.x & 63] = s; ls2[g][threadIdx.x & 63] = s2;
    __syncthreads();
    if (g == 0 && c < CC) {
        int cx = threadIdx.x & 63;
        s = ls[0][cx] + ls[1][cx] + ls[2][cx] + ls[3][cx];
        s2 = ls2[0][cx] + ls2[1][cx] + ls2[2][cx] + ls2[3][cx];
        float mu = s / (float)TT;
        float var = s2 / (float)TT - mu * mu;
        mean[b * CC + c] = mu;
        stdev[b * CC + c] = sqrtf(var + 1e-5f);
    }
}

// ============ build tokb[B,866,736] bf16: normalized channels + marks, K-padded ============
__global__ __launch_bounds__(256) void build_tok(const float* __restrict__ x_enc,
                                                 const float* __restrict__ x_mark,
                                                 const float* __restrict__ mean,
                                                 const float* __restrict__ stdev,
                                                 const float* __restrict__ rw,
                                                 const float* __restrict__ rb,
                                                 ushort_t* __restrict__ tok) {
    int b = blockIdx.z;
    int r0 = blockIdx.x * 32, t0 = blockIdx.y * 32;
    __shared__ float tile[32][33];
    int tx = threadIdx.x & 31, ty = threadIdx.x >> 5;
    #pragma unroll
    for (int kk = 0; kk < 4; kk++) {
        int t = t0 + ty + kk * 8, r = r0 + tx;
        float v = 0.f;
        if (t < TT && r < LTOK) {
            if (r < CC) {
                float xv = x_enc[((size_t)b * TT + t) * CC + r];
                v = (xv - mean[b * CC + r]) / stdev[b * CC + r] * rw[r] + rb[r];
            } else {
                v = x_mark[((size_t)b * TT + t) * MM + (r - CC)];
            }
        }
        tile[ty + kk * 8][tx] = v;
    }
    __syncthreads();
    #pragma unroll
    for (int kk = 0; kk < 4; kk++) {
        int r = r0 + ty + kk * 8, t = t0 + tx;
        if (r < LTOK && t < KPAD)
            tok[((size_t)b * LTOK + r) * KPAD + t] = f2b(tile[tx][ty + kk * 8]);
    }
}

// ============ weight convert+transpose: W[K,N] f32 -> Wt[NP,KP] bf16 (zero-padded) ============
__global__ __launch_bounds__(256) void convT(const float* __restrict__ W,
                                             ushort_t* __restrict__ Wt,
                                             int K, int N, int KP, int NP) {
    __shared__ float tile[32][33];
    int k0 = blockIdx.x * 32, n0 = blockIdx.y * 32;
    int tx = threadIdx.x & 31, ty = threadIdx.x >> 5;
    #pragma unroll
    for (int r = 0; r < 4; r++) {
        int k = k0 + ty + r * 8, n = n0 + tx;
        tile[ty + r * 8][tx] = (k < K && n < N) ? W[(size_t)k * N + n] : 0.f;
    }
    __syncthreads();
    #pragma unroll
    for (int r = 0; r < 4; r++) {
        int n = n0 + ty + r * 8, k = k0 + tx;
        if (n < NP && k < KP)
            Wt[(size_t)n * KP + k] = f2b(tile[tx][ty + r * 8]);
    }
}

// ============ bf16 MFMA GEMM: C = act(A[M,K] @ Bt[N,K]^T + bias) ============
// 128x128 tile, BK=32, 4 waves (2x2 of 64x64), mfma_f32_16x16x32_bf16.
// ACT: 0 none, 1 gelu(exact), 2 sigmoid. OF: write f32 Cf. OB: write bf16 Cb.
#define GLL(g, l) __builtin_amdgcn_global_load_lds( \
    (const __attribute__((address_space(1))) void*)(g), \
    (__attribute__((address_space(3))) void*)(l), 16, 0, 0)

template <int ACT, bool OF, bool OB>
__global__ __launch_bounds__(256) void bgemm(const ushort_t* __restrict__ A,
                                             const ushort_t* __restrict__ Bt,
                                             const float* __restrict__ bias,
                                             float* __restrict__ Cf,
                                             ushort_t* __restrict__ Cb,
                                             int Mdim, int Kdim, int Nout) {
    __shared__ ushort_t As[128 * 32];
    __shared__ ushort_t Bs[128 * 32];
    const int tid = threadIdx.x;
    const int lane = tid & 63;
    const int wid = tid >> 6;
    const int m0 = blockIdx.y * 128;
    const int n0 = blockIdx.x * 128;
    const int wm = wid & 1, wn = wid >> 1;

    f4v acc[4][4];
    #pragma unroll
    for (int i = 0; i < 4; i++)
        #pragma unroll
        for (int j = 0; j < 4; j++)
            acc[i][j] = (f4v){0.f, 0.f, 0.f, 0.f};

    // staging: per wave, 2 instructions for A (16 rows x 32k each) + 2 for B
    const int srow = wid * 16 + (lane >> 2);
    const int skq = (lane & 3) * 8;
    int ar0 = m0 + srow;       if (ar0 > Mdim - 1) ar0 = Mdim - 1;
    int ar1 = m0 + 64 + srow;  if (ar1 > Mdim - 1) ar1 = Mdim - 1;
    const ushort_t* gA0 = A + (size_t)ar0 * Kdim + skq;
    const ushort_t* gA1 = A + (size_t)ar1 * Kdim + skq;
    const ushort_t* gB0 = Bt + (size_t)(n0 + srow) * Kdim + skq;
    const ushort_t* gB1 = Bt + (size_t)(n0 + 64 + srow) * Kdim + skq;
    ushort_t* lA0 = &As[(wid * 16) * 32];
    ushort_t* lA1 = &As[(64 + wid * 16) * 32];
    ushort_t* lB0 = &Bs[(wid * 16) * 32];
    ushort_t* lB1 = &Bs[(64 + wid * 16) * 32];

    const int lr = lane & 15;
    const int kc = (lane >> 4) * 8;

    for (int k0 = 0; k0 < Kdim; k0 += 32) {
        GLL(gA0 + k0, lA0);
        GLL(gA1 + k0, lA1);
        GLL(gB0 + k0, lB0);
        GLL(gB1 + k0, lB1);
        __syncthreads();
        s8v af[4], bf[4];
        #pragma unroll
        for (int i = 0; i < 4; i++)
            af[i] = *(const s8v*)&As[(wm * 64 + i * 16 + lr) * 32 + kc];
        #pragma unroll
        for (int j = 0; j < 4; j++)
            bf[j] = *(const s8v*)&Bs[(wn * 64 + j * 16 + lr) * 32 + kc];
        #pragma unroll
        for (int i = 0; i < 4; i++)
            #pragma unroll
            for (int j = 0; j < 4; j++)
                acc[i][j] = __builtin_amdgcn_mfma_f32_16x16x32_bf16(af[i], bf[j], acc[i][j], 0, 0, 0);
        __syncthreads();
    }

    // epilogue: C/D layout col=lane&15, row=(lane>>4)*4+reg
    const int orow = (lane >> 4) * 4;
    #pragma unroll
    for (int j = 0; j < 4; j++) {
        int col = n0 + wn * 64 + j * 16 + lr;
        bool cok = col < Nout;
        float bb = cok ? bias[col] : 0.f;
        #pragma unroll
        for (int i = 0; i < 4; i++) {
            #pragma unroll
            for (int r = 0; r < 4; r++) {
                int row = m0 + wm * 64 + i * 16 + orow + r;
                if (cok && row < Mdim) {
                    float v = acc[i][j][r] + bb;
                    if (ACT == 1) v = 0.5f * v * (1.0f + erff(v * 0.70710678118654752f));
                    if (ACT == 2) v = 1.0f / (1.0f + expf(-v));
                    size_t idx = (size_t)row * Nout + col;
                    if (OF) Cf[idx] = v;
                    if (OB) Cb[idx] = f2b(v);
                }
            }
        }
    }
}

// ============ LayerNorm over D=512: x_f32 = LN(x + res_bf16); also write bf16 copy ============
__global__ __launch_bounds__(256) void ln_kernel(float* __restrict__ x,
                                                 const ushort_t* __restrict__ res,
                                                 const float* __restrict__ w,
                                                 const float* __restrict__ bp,
                                                 ushort_t* __restrict__ xb) {
    size_t base = (size_t)blockIdx.x * DD;
    int tid = threadIdx.x;
    float v0 = x[base + tid];
    float v1 = x[base + tid + 256];
    if (res != nullptr) { v0 += b2f(res[base + tid]); v1 += b2f(res[base + tid + 256]); }
    float s = wave_sum(v0 + v1);
    float s2 = wave_sum(v0 * v0 + v1 * v1);
    __shared__ float a1[4], a2[4];
    if ((tid & 63) == 0) { a1[tid >> 6] = s; a2[tid >> 6] = s2; }
    __syncthreads();
    s = a1[0] + a1[1] + a1[2] + a1[3];
    s2 = a2[0] + a2[1] + a2[2] + a2[3];
    float mu = s * (1.0f / DD);
    float var = s2 * (1.0f / DD) - mu * mu;
    float rs = rsqrtf(var + 1e-5f);
    float o0 = (v0 - mu) * rs * w[tid] + bp[tid];
    float o1 = (v1 - mu) * rs * w[tid + 256] + bp[tid + 256];
    x[base + tid] = o0;
    x[base + tid + 256] = o1;
    xb[base + tid] = f2b(o0);
    xb[base + tid + 256] = f2b(o1);
}

// ============ attention: per (b,h) column sums over l (optionally weighted) ============
template <bool WEIGHTED>
__global__ __launch_bounds__(256) void attn_sums(const ushort_t* __restrict__ Q,
                                                 const ushort_t* __restrict__ Kp,
                                                 const float* __restrict__ wq,
                                                 const float* __restrict__ wk,
                                                 float* __restrict__ qsum,
                                                 float* __restrict__ ksum) {
    int bh = blockIdx.x;
    int b = bh >> 3, h = bh & 7;
    int e = threadIdx.x & 63, g = threadIdx.x >> 6;
    const size_t base = ((size_t)b * LTOK) * DD + h * 64 + e;
    float sq = 0.f, sk = 0.f;
    for (int l = g; l < LTOK; l += 4) {
        float qv = b2f(Q[base + (size_t)l * DD]);
        float kv = b2f(Kp[base + (size_t)l * DD]);
        if (WEIGHTED) { qv *= wq[bh * LTOK + l]; kv *= wk[bh * LTOK + l]; }
        sq += qv; sk += kv;
    }
    __shared__ float s1[4][64], s2[4][64];
    s1[g][e] = sq; s2[g][e] = sk;
    __syncthreads();
    if (g == 0) {
        sq = s1[0][e] + s1[1][e] + s1[2][e] + s1[3][e];
        sk = s2[0][e] + s2[1][e] + s2[2][e] + s2[3][e];
        qsum[bh * 64 + e] = sq;
        ksum[bh * 64 + e] = sk;
    }
}

// ============ attention: per-l dot with summed vector ============
template <int MODE>
__global__ __launch_bounds__(256) void attn_dots(const ushort_t* __restrict__ Q,
                                                 const ushort_t* __restrict__ Kp,
                                                 const float* __restrict__ Sq,
                                                 const float* __restrict__ Sk,
                                                 float* __restrict__ outq,
                                                 float* __restrict__ outk) {
    int bh = blockIdx.x;
    int b = bh >> 3, h = bh & 7;
    int lane = threadIdx.x & 63, w = threadIdx.x >> 6;
    float sq = Sq[bh * 64 + lane] + 1e-6f;
    float sk = Sk[bh * 64 + lane] + 1e-6f;
    const size_t base = ((size_t)b * LTOK) * DD + h * 64 + lane;
    int l0 = blockIdx.y * 64 + w * 16;
    for (int i = 0; i < 16; i++) {
        int l = l0 + i;
        if (l >= LTOK) break;
        float dq = (b2f(Q[base + (size_t)l * DD]) + 1e-6f) * sq;
        float dk = (b2f(Kp[base + (size_t)l * DD]) + 1e-6f) * sk;
        dq = wave_sum(dq);
        dk = wave_sum(dk);
        if (lane == 0) {
            if (MODE == 0) { outq[bh * LTOK + l] = 1.0f / dq; outk[bh * LTOK + l] = 1.0f / dk; }
            else { outq[bh * LTOK + l] = 1.0f / (1.0f + expf(-dq)); outk[bh * LTOK + l] = dk; }
        }
    }
}

// ============ attention: softmax over s (in place), scaled by Ls ============
__global__ __launch_bounds__(256) void attn_softmax(float* __restrict__ buf) {
    float* p = buf + (size_t)blockIdx.x * LTOK;
    int tid = threadIdx.x;
    __shared__ float red[4];
    float mx = -1e30f;
    for (int l = tid; l < LTOK; l += 256) mx = fmaxf(mx, p[l]);
    #pragma unroll
    for (int off = 32; off; off >>= 1) mx = fmaxf(mx, __shfl_xor(mx, off, 64));
    if ((tid & 63) == 0) red[tid >> 6] = mx;
    __syncthreads();
    mx = fmaxf(fmaxf(red[0], red[1]), fmaxf(red[2], red[3]));
    __syncthreads();
    float s = 0.f;
    for (int l = tid; l < LTOK; l += 256) s += expf(p[l] - mx);
    s = wave_sum(s);
    if ((tid & 63) == 0) red[tid >> 6] = s;
    __syncthreads();
    s = red[0] + red[1] + red[2] + red[3];
    float scale = (float)LTOK / s;
    for (int l = tid; l < LTOK; l += 256) p[l] = expf(p[l] - mx) * scale;
}

// ============ attention: kv[e,d] = sum_s k[s,e] * v[s,d] * ncref[s] ============
__global__ __launch_bounds__(256) void attn_kv(const ushort_t* __restrict__ Kp,
                                               const ushort_t* __restrict__ V,
                                               const float* __restrict__ ncref,
                                               float* __restrict__ kv) {
    int bh = blockIdx.x;
    int b = bh >> 3, h = bh & 7;
    int d = threadIdx.x & 63, eg = threadIdx.x >> 6;
    __shared__ float ks[8][64], vs[8][64];
    float acc[16] = {};
    const size_t base = ((size_t)b * LTOK) * DD + h * 64;
    for (int s0 = 0; s0 < LTOK; s0 += 8) {
        __syncthreads();
        #pragma unroll
        for (int j = 0; j < 2; j++) {
            int idx = threadIdx.x + j * 256;
            int s = s0 + (idx >> 6), e = idx & 63;
            float kvl = 0.f, vvl = 0.f;
            if (s < LTOK) {
                kvl = b2f(Kp[base + (size_t)s * DD + e]);
                vvl = b2f(V[base + (size_t)s * DD + e]) * ncref[bh * LTOK + s];
            }
            ks[idx >> 6][e] = kvl;
            vs[idx >> 6][e] = vvl;
        }
        __syncthreads();
        #pragma unroll
        for (int si = 0; si < 8; si++) {
            float vv = vs[si][d];
            #pragma unroll
            for (int i = 0; i < 16; i++) acc[i] += ks[si][eg * 16 + i] * vv;
        }
    }
    #pragma unroll
    for (int i = 0; i < 16; i++)
        kv[(size_t)bh * 4096 + (eg * 16 + i) * 64 + d] = acc[i];
}

// ============ attention: out[l,d] = dot(q[l,:], kv[:,d]) * nr[l]*nrref[l], bf16 out ============
__global__ __launch_bounds__(256) void attn_out(const ushort_t* __restrict__ Q,
                                                const float* __restrict__ kv,
                                                const float* __restrict__ nr,
                                                const float* __restrict__ nrref,
                                                ushort_t* __restrict__ out) {
    int bh = blockIdx.x;
    int b = bh >> 3, h = bh & 7;
    int d = threadIdx.x & 63, lg = threadIdx.x >> 6;
    __shared__ float kvs[64][64];
    __shared__ float qs[64][64];
    #pragma unroll
    for (int j = 0; j < 16; j++) {
        int idx = threadIdx.x + j * 256;
        kvs[idx >> 6][idx & 63] = kv[(size_t)bh * 4096 + idx];
    }
    int l0 = blockIdx.y * 64;
    const size_t base = ((size_t)b * LTOK) * DD + h * 64;
    for (int j = 0; j < 16; j++) {
        int idx = threadIdx.x + j * 256;
        int lr = idx >> 6, e = idx & 63;
        int l = l0 + lr;
        qs[lr][e] = (l < LTOK) ? b2f(Q[base + (size_t)l * DD + e]) : 0.f;
    }
    __syncthreads();
    for (int i = 0; i < 16; i++) {
        int lr = lg * 16 + i;
        int l = l0 + lr;
        if (l >= LTOK) continue;
        float acc = 0.f;
        #pragma unroll
        for (int e = 0; e < 64; e++) acc += qs[lr][e] * kvs[e][d];
        float sc = nr[bh * LTOK + l] * nrref[bh * LTOK + l];
        out[base + (size_t)l * DD + d] = f2b(acc * sc);
    }
}

// ============ final: transpose from projb[NTOK,720] bf16, RevIN denorm ============
__global__ __launch_bounds__(256) void final_out(const ushort_t* __restrict__ p,
                                                 const float* __restrict__ mean,
                                                 const float* __restrict__ stdev,
                                                 const float* __restrict__ rw,
                                                 const float* __restrict__ rb,
                                                 float* __restrict__ out) {
    int b = blockIdx.z;
    int c0 = blockIdx.x * 32, t0 = blockIdx.y * 32;
    __shared__ float tile[32][33];
    int tx = threadIdx.x & 31, ty = threadIdx.x >> 5;
    #pragma unroll
    for (int kk = 0; kk < 4; kk++) {
        int c = c0 + ty + kk * 8, t = t0 + tx;
        float v = 0.f;
        if (c < CC && t < TT) v = b2f(p[((size_t)b * LTOK + c) * TT + t]);
        tile[ty + kk * 8][tx] = v;
    }
    __syncthreads();
    #pragma unroll
    for (int kk = 0; kk < 4; kk++) {
        int t = t0 + ty + kk * 8, c = c0 + tx;
        if (c < CC && t < TT) {
            float v = tile[tx][ty + kk * 8];
            v = (v - rb[c]) / (rw[c] + 1e-10f);
            v = v * stdev[b * CC + c] + mean[b * CC + c];
            out[((size_t)b * TT + t) * CC + c] = v;
        }
    }
}

extern "C" void kernel_launch(void* const* d_in, const int* in_sizes, int n_in,
                              void* d_out, int out_size, void* d_ws, size_t ws_size,
                              hipStream_t stream) {
    (void)in_sizes; (void)n_in; (void)out_size; (void)ws_size;
    const float* x_enc   = (const float*)d_in[0];
    const float* x_mark  = (const float*)d_in[1];
    const float* revin_w = (const float*)d_in[4];
    const float* revin_b = (const float*)d_in[5];
    const float* emb_W   = (const float*)d_in[6];
    const float* emb_b   = (const float*)d_in[7];
    const float* Wq = (const float*)d_in[8];
    const float* bq = (const float*)d_in[9];
    const float* Wk = (const float*)d_in[10];
    const float* bk = (const float*)d_in[11];
    const float* Wv = (const float*)d_in[12];
    const float* bv = (const float*)d_in[13];
    const float* Wo = (const float*)d_in[14];
    const float* bo = (const float*)d_in[15];
    const float* ff1_W = (const float*)d_in[16];
    const float* ff1_b = (const float*)d_in[17];
    const float* ff2_W = (const float*)d_in[18];
    const float* ff2_b = (const float*)d_in[19];
    const float* ln1_w = (const float*)d_in[20];
    const float* ln1_b = (const float*)d_in[21];
    const float* ln2_w = (const float*)d_in[22];
    const float* ln2_b = (const float*)d_in[23];
    const float* lnf_w = (const float*)d_in[24];
    const float* lnf_b = (const float*)d_in[25];
    const float* proj_W = (const float*)d_in[26];
    const float* proj_b = (const float*)d_in[27];
    float* out = (float*)d_out;

    // ---- workspace layout (~240 MB) ----
    char* wsb = (char*)d_ws;
    size_t off = 0;
    auto alloc = [&](size_t bytes) {
        off = (off + 63) & ~(size_t)63;
        void* p = wsb + off; off += bytes; return p;
    };
    float* mean  = (float*)alloc((size_t)BB * CC * 4);
    float* stdev = (float*)alloc((size_t)BB * CC * 4);
    float* qsum  = (float*)alloc((size_t)NBH * 64 * 4);
    float* ksum  = (float*)alloc((size_t)NBH * 64 * 4);
    float* qnsum = (float*)alloc((size_t)NBH * 64 * 4);
    float* knsum = (float*)alloc((size_t)NBH * 64 * 4);
    float* nr    = (float*)alloc((size_t)NBH * LTOK * 4);
    float* nc    = (float*)alloc((size_t)NBH * LTOK * 4);
    float* nrref = (float*)alloc((size_t)NBH * LTOK * 4);
    float* ncref = (float*)alloc((size_t)NBH * LTOK * 4);
    float* kvbuf = (float*)alloc((size_t)NBH * 4096 * 4);
    float* x     = (float*)alloc((size_t)NTOK * DD * 4);         // fp32 residual spine
    ushort_t* xb = (ushort_t*)alloc((size_t)NTOK * DD * 2);      // bf16 copy of x
    ushort_t* qb = (ushort_t*)alloc((size_t)NTOK * DD * 2);      // also Wo/FF2 output (tmpb)
    ushort_t* kb = (ushort_t*)alloc((size_t)NTOK * DD * 2);
    ushort_t* vb = (ushort_t*)alloc((size_t)NTOK * DD * 2);      // also attention output
    ushort_t* wbuf = (ushort_t*)alloc((size_t)10207232 * 2);     // all bf16 transposed weights
    ushort_t* U  = (ushort_t*)alloc((size_t)NTOK * KPAD * 2);    // union: tokb / ff-chunk / projb

    // weight sub-buffers
    ushort_t* embT = wbuf;                          // [512,736]
    ushort_t* qT   = embT + (size_t)512 * KPAD;     // 3 x [512,512]
    ushort_t* kT   = qT + 3 * 262144;
    ushort_t* vT   = kT + 3 * 262144;
    ushort_t* oT   = vT + 3 * 262144;
    ushort_t* f1T  = oT + 3 * 262144;               // 3 x [2048,512]
    ushort_t* f2T  = f1T + (size_t)3 * 1048576;     // 3 x [512,2048]
    ushort_t* pT   = f2T + (size_t)3 * 1048576;     // [768,512]
    ushort_t* tokb  = U;                             // [NTOK, 736]
    ushort_t* ffb   = U;                             // chunk [6912, 2048]
    ushort_t* projb = U;                             // [NTOK, 720]
    ushort_t* tmpb  = qb;                            // Wo/FF2 output

    dim3 blk(256);
    // ---- weight conversion (transpose to [N,K] bf16) ----
    auto cvt = [&](const float* W, ushort_t* Wt, int K, int N, int KP, int NP) {
        convT<<<dim3((KP + 31) / 32, (NP + 31) / 32), blk, 0, stream>>>(W, Wt, K, N, KP, NP);
    };
    cvt(emb_W, embT, TT, DD, KPAD, DD);
    for (int l = 0; l < 3; l++) {
        cvt(Wq + (size_t)l * DD * DD, qT + (size_t)l * 262144, DD, DD, DD, DD);
        cvt(Wk + (size_t)l * DD * DD, kT + (size_t)l * 262144, DD, DD, DD, DD);
        cvt(Wv + (size_t)l * DD * DD, vT + (size_t)l * 262144, DD, DD, DD, DD);
        cvt(Wo + (size_t)l * DD * DD, oT + (size_t)l * 262144, DD, DD, DD, DD);
        cvt(ff1_W + (size_t)l * DD * FFD, f1T + (size_t)l * 1048576, DD, FFD, DD, FFD);
        cvt(ff2_W + (size_t)l * FFD * DD, f2T + (size_t)l * 1048576, FFD, DD, FFD, DD);
    }
    cvt(proj_W, pT, DD, TT, DD, NPADP);

    // ---- RevIN + tokens + embedding ----
    revin_stats<<<dim3((CC + 63) / 64, BB), blk, 0, stream>>>(x_enc, mean, stdev);
    build_tok<<<dim3((LTOK + 31) / 32, (KPAD + 31) / 32, BB), blk, 0, stream>>>(
        x_enc, x_mark, mean, stdev, revin_w, revin_b, tokb);
    const int MT = (NTOK + 127) / 128;   // 217
    bgemm<0, true, true><<<dim3(DD / 128, MT), blk, 0, stream>>>(
        tokb, embT, emb_b, x, xb, NTOK, KPAD, DD);

    int ltiles = (LTOK + 63) / 64;
    for (int l = 0; l < 3; l++) {
        bgemm<2, false, true><<<dim3(DD / 128, MT), blk, 0, stream>>>(
            xb, qT + (size_t)l * 262144, bq + l * DD, nullptr, qb, NTOK, DD, DD);
        bgemm<2, false, true><<<dim3(DD / 128, MT), blk, 0, stream>>>(
            xb, kT + (size_t)l * 262144, bk + l * DD, nullptr, kb, NTOK, DD, DD);
        bgemm<0, false, true><<<dim3(DD / 128, MT), blk, 0, stream>>>(
            xb, vT + (size_t)l * 262144, bv + l * DD, nullptr, vb, NTOK, DD, DD);
        attn_sums<false><<<NBH, blk, 0, stream>>>(qb, kb, nullptr, nullptr, qsum, ksum);
        attn_dots<0><<<dim3(NBH, ltiles), blk, 0, stream>>>(qb, kb, ksum, qsum, nr, nc);
        attn_sums<true><<<NBH, blk, 0, stream>>>(qb, kb, nr, nc, qnsum, knsum);
        attn_dots<1><<<dim3(NBH, ltiles), blk, 0, stream>>>(qb, kb, knsum, qnsum, nrref, ncref);
        attn_softmax<<<NBH, blk, 0, stream>>>(ncref);
        attn_kv<<<NBH, blk, 0, stream>>>(kb, vb, ncref, kvbuf);
        attn_out<<<dim3(NBH, ltiles), blk, 0, stream>>>(qb, kvbuf, nr, nrref, vb);
        // Wo: A = attention output (vb), out -> tmpb (qb, dead)
        bgemm<0, false, true><<<dim3(DD / 128, MT), blk, 0, stream>>>(
            vb, oT + (size_t)l * 262144, bo + l * DD, nullptr, tmpb, NTOK, DD, DD);
        ln_kernel<<<NTOK, blk, 0, stream>>>(x, tmpb, ln1_w + l * DD, ln1_b + l * DD, xb);
        // FF chunked over rows (ff activation fits in U)
        for (int t0 = 0; t0 < NTOK / 64; t0 += 108) {
            int nt = NTOK / 64 - t0; if (nt > 108) nt = 108;
            int rs = t0 * 64, mc = nt * 64;
            bgemm<1, false, true><<<dim3(FFD / 128, (mc + 127) / 128), blk, 0, stream>>>(
                xb + (size_t)rs * DD, f1T + (size_t)l * 1048576, ff1_b + l * FFD,
                nullptr, ffb, mc, DD, FFD);
            bgemm<0, false, true><<<dim3(DD / 128, (mc + 127) / 128), blk, 0, stream>>>(
                ffb, f2T + (size_t)l * 1048576, ff2_b + l * DD,
                nullptr, tmpb + (size_t)rs * DD, mc, FFD, DD);
        }
        ln_kernel<<<NTOK, blk, 0, stream>>>(x, tmpb, ln2_w + l * DD, ln2_b + l * DD, xb);
    }
    ln_kernel<<<NTOK, blk, 0, stream>>>(x, nullptr, lnf_w, lnf_b, xb);
    // projection: [NTOK,512] @ [512,768(pad)] -> projb [NTOK,720] bf16
    bgemm<0, false, true><<<dim3(NPADP / 128, MT), blk, 0, stream>>>(
        xb, pT, proj_b, nullptr, projb, NTOK, DD, TT);
    final_out<<<dim3((CC + 31) / 32, (TT + 31) / 32, BB), blk, 0, stream>>>(
        projb, mean, stdev, revin_w, revin_b, out);
}